// Round 1
// baseline (325.245 us; speedup 1.0000x reference)
//
#include <hip/hip_runtime.h>
#include <hip/hip_bf16.h>

// Self_Attention: conv1d(k=7,pad=3)+BN on q/k/v -> MHA (H=8, DH=64) -> LayerNorm
// Strategy: bf16 MFMA (16x16x32) for conv-as-GEMM and attention; fp32 accum.
// ws layout: qh|kh|vh bf16 [4][2048][512] each, w_eff bf16 [7][512][512], b_eff f32[512]

#define B_ 4
#define S_ 2048
#define DIN_ 512
#define DOUT_ 512
#define H_ 8
#define DH_ 64
#define EPS_ 1e-5f

using bf16x8 = __attribute__((ext_vector_type(8))) short;
using f32x4  = __attribute__((ext_vector_type(4))) float;

__device__ __forceinline__ unsigned short f2bf(float x) {
    union { float f; unsigned u; } v; v.f = x;
    unsigned r = v.u + 0x7FFF + ((v.u >> 16) & 1);
    return (unsigned short)(r >> 16);
}

// ---------------- kernel 1: fold BN into weights, cast to bf16 [t][co][ci] ----
__global__ void prep_w(const float* __restrict__ w, const float* __restrict__ cb,
                       const float* __restrict__ gamma, const float* __restrict__ beta,
                       const float* __restrict__ mean, const float* __restrict__ var,
                       unsigned short* __restrict__ w_eff, float* __restrict__ b_eff) {
    int gid = blockIdx.x * blockDim.x + threadIdx.x;
    if (gid < DOUT_) {
        float sc = gamma[gid] * rsqrtf(var[gid] + EPS_);
        b_eff[gid] = (cb[gid] - mean[gid]) * sc + beta[gid];
    }
    int total = 7 * DOUT_ * DIN_;
    for (int i = gid; i < total; i += gridDim.x * blockDim.x) {
        int t = i / (DOUT_ * DIN_);
        int rem = i - t * (DOUT_ * DIN_);
        int co = rem >> 9;          // /512
        int ci = rem & 511;
        float sc = gamma[co] * rsqrtf(var[co] + EPS_);
        w_eff[i] = f2bf(w[(co * DIN_ + ci) * 7 + t] * sc);
    }
}

// ---------------- kernel 2: conv+BN as implicit GEMM (7 shifted K=512 GEMMs) --
// 128x128 tile, 4 waves (each 64x64 = 4x4 frags), A staged once per ci-chunk.
__global__ void conv_bn(const float* __restrict__ q, const float* __restrict__ k,
                        const float* __restrict__ v,
                        const unsigned short* __restrict__ w_eff,
                        const float* __restrict__ b_eff,
                        unsigned short* __restrict__ out3) {
    __shared__ alignas(16) unsigned short As[134][72];  // rows s0-3 .. s0+130, 64 ci (+8 pad)
    __shared__ alignas(16) unsigned short Bs[128][72];  // 128 co x 64 ci (+8 pad)

    int bid = blockIdx.x;
    int tensor = bid >> 8;            // 256 blocks per tensor
    int rem = bid & 255;
    int batch = rem >> 6;
    int stile = (rem >> 2) & 15;
    int cotile = rem & 3;
    const float* x = (tensor == 0) ? q : ((tensor == 1) ? k : v);
    x += (size_t)batch * S_ * DIN_;
    unsigned short* out = out3 + (size_t)tensor * (B_ * S_ * DOUT_) + (size_t)batch * S_ * DOUT_;
    int s0 = stile * 128;
    int co0 = cotile * 128;
    int tid = threadIdx.x;
    int lane = tid & 63;
    int wv = tid >> 6;
    int wrow = (wv >> 1) * 64;
    int wcol = (wv & 1) * 64;

    f32x4 acc[4][4] = {};

    for (int cic = 0; cic < 8; ++cic) {
        int ci0 = cic * 64;
        __syncthreads();
        // stage A: 134 rows x 64 ci, f32 -> bf16 (zero-pad outside [0,S))
        for (int c = tid; c < 134 * 16; c += 256) {
            int ar = c >> 4;
            int cc = c & 15;
            int gr = s0 + ar - 3;
            float4 val = make_float4(0.f, 0.f, 0.f, 0.f);
            if (gr >= 0 && gr < S_)
                val = *reinterpret_cast<const float4*>(&x[(size_t)gr * DIN_ + ci0 + cc * 4]);
            unsigned short* d = &As[ar][cc * 4];
            d[0] = f2bf(val.x); d[1] = f2bf(val.y); d[2] = f2bf(val.z); d[3] = f2bf(val.w);
        }
        for (int t = 0; t < 7; ++t) {
            if (t) __syncthreads();
            // stage B: w_eff[t][co0+r][ci0..ci0+64), bf16 16B chunks
            for (int c = tid; c < 1024; c += 256) {
                int r = c >> 3;
                int cc = c & 7;
                *reinterpret_cast<uint4*>(&Bs[r][cc * 8]) =
                    *reinterpret_cast<const uint4*>(
                        &w_eff[(size_t)t * DOUT_ * DIN_ + (size_t)(co0 + r) * DIN_ + ci0 + cc * 8]);
            }
            __syncthreads();
            for (int kk = 0; kk < 2; ++kk) {
                int krow = kk * 32 + 8 * (lane >> 4);
                bf16x8 af[4], bfr[4];
                for (int m = 0; m < 4; ++m)
                    af[m] = *reinterpret_cast<const bf16x8*>(&As[wrow + m * 16 + (lane & 15) + t][krow]);
                for (int n = 0; n < 4; ++n)
                    bfr[n] = *reinterpret_cast<const bf16x8*>(&Bs[wcol + n * 16 + (lane & 15)][krow]);
                for (int m = 0; m < 4; ++m)
                    for (int n = 0; n < 4; ++n)
                        acc[m][n] = __builtin_amdgcn_mfma_f32_16x16x32_bf16(af[m], bfr[n], acc[m][n], 0, 0, 0);
            }
        }
    }
    // epilogue: + effective bias, cast bf16, store [s][co]
    for (int m = 0; m < 4; ++m) {
        int row = s0 + wrow + m * 16 + 4 * (lane >> 4);
        for (int n = 0; n < 4; ++n) {
            int col = co0 + wcol + n * 16 + (lane & 15);
            float be = b_eff[col];
            for (int r = 0; r < 4; ++r)
                out[(size_t)(row + r) * DOUT_ + col] = f2bf(acc[m][n][r] + be);
        }
    }
}

// ---------------- kernel 3: flash attention, QBLK=64 (wave per 16 rows), KBLK=64
__global__ void attn(const unsigned short* __restrict__ qh,
                     const unsigned short* __restrict__ kh,
                     const unsigned short* __restrict__ vh,
                     float* __restrict__ out) {
    __shared__ alignas(16) unsigned short Ks[64][72];      // [key][dh]
    __shared__ alignas(16) unsigned short Vt[64][72];      // [dh][key]
    __shared__ alignas(16) unsigned short Ps[4][16][72];   // per-wave P (16 rows x 64 keys)

    int bid = blockIdx.x;
    int qt = bid & 31;
    int bh = bid >> 5;
    int b = bh >> 3;
    int h = bh & 7;
    int tid = threadIdx.x;
    int lane = tid & 63;
    int wv = tid >> 6;
    int s0 = qt * 64;

    const unsigned short* qp = qh + (size_t)b * S_ * DOUT_ + h * DH_;
    const unsigned short* kp = kh + (size_t)b * S_ * DOUT_ + h * DH_;
    const unsigned short* vp = vh + (size_t)b * S_ * DOUT_ + h * DH_;

    // Q fragments held in registers: rows s0 + wv*16 + (lane&15)
    bf16x8 qf[2];
    {
        int row = s0 + wv * 16 + (lane & 15);
        for (int kkk = 0; kkk < 2; ++kkk)
            qf[kkk] = *reinterpret_cast<const bf16x8*>(
                &qp[(size_t)row * DOUT_ + kkk * 32 + 8 * (lane >> 4)]);
    }

    f32x4 oacc[4] = {};
    float mrow[4], lrow[4];
    for (int r = 0; r < 4; ++r) { mrow[r] = -1e30f; lrow[r] = 0.f; }
    const float scale = 0.125f; // 1/sqrt(64)

    for (int kt = 0; kt < S_ / 64; ++kt) {
        __syncthreads();
        // stage K tile [64][64]
        for (int c = tid; c < 512; c += 256) {
            int key = c >> 3, cc = c & 7;
            *reinterpret_cast<uint4*>(&Ks[key][cc * 8]) =
                *reinterpret_cast<const uint4*>(&kp[(size_t)(kt * 64 + key) * DOUT_ + cc * 8]);
        }
        // stage V transposed [dh][key]
        for (int c = tid; c < 512; c += 256) {
            int key = c >> 3, cc = c & 7;
            uint4 raw = *reinterpret_cast<const uint4*>(&vp[(size_t)(kt * 64 + key) * DOUT_ + cc * 8]);
            const unsigned short* e = reinterpret_cast<const unsigned short*>(&raw);
            for (int j = 0; j < 8; ++j) Vt[cc * 8 + j][key] = e[j];
        }
        __syncthreads();

        // S = Q K^T (16 rows x 64 keys per wave)
        f32x4 sf[4] = {};
        for (int kkk = 0; kkk < 2; ++kkk) {
            int krow = kkk * 32 + 8 * (lane >> 4);
            for (int n = 0; n < 4; ++n) {
                bf16x8 kf = *reinterpret_cast<const bf16x8*>(&Ks[n * 16 + (lane & 15)][krow]);
                sf[n] = __builtin_amdgcn_mfma_f32_16x16x32_bf16(qf[kkk], kf, sf[n], 0, 0, 0);
            }
        }
        for (int n = 0; n < 4; ++n)
            for (int r = 0; r < 4; ++r) sf[n][r] *= scale;

        // online softmax; row r of this lane-group = 4*(lane>>4)+r
        float mnew[4], corr[4];
        for (int r = 0; r < 4; ++r) {
            float mx = fmaxf(fmaxf(sf[0][r], sf[1][r]), fmaxf(sf[2][r], sf[3][r]));
            for (int off = 1; off < 16; off <<= 1)
                mx = fmaxf(mx, __shfl_xor(mx, off, 64));
            mnew[r] = fmaxf(mrow[r], mx);
            corr[r] = __expf(mrow[r] - mnew[r]);
            mrow[r] = mnew[r];
        }
        float rs[4] = {0.f, 0.f, 0.f, 0.f};
        for (int n = 0; n < 4; ++n)
            for (int r = 0; r < 4; ++r) {
                float p = __expf(sf[n][r] - mnew[r]);
                sf[n][r] = p;
                rs[r] += p;
            }
        for (int r = 0; r < 4; ++r) {
            for (int off = 1; off < 16; off <<= 1)
                rs[r] += __shfl_xor(rs[r], off, 64);
            lrow[r] = lrow[r] * corr[r] + rs[r];
            for (int n = 0; n < 4; ++n) oacc[n][r] *= corr[r];
        }
        // P -> LDS (D layout -> A layout relayout)
        for (int n = 0; n < 4; ++n)
            for (int r = 0; r < 4; ++r)
                Ps[wv][4 * (lane >> 4) + r][n * 16 + (lane & 15)] = f2bf(sf[n][r]);
        __syncthreads();
        // O += P V
        for (int kkk = 0; kkk < 2; ++kkk) {
            int krow = kkk * 32 + 8 * (lane >> 4);
            bf16x8 pf = *reinterpret_cast<const bf16x8*>(&Ps[wv][lane & 15][krow]);
            for (int n = 0; n < 4; ++n) {
                bf16x8 vf = *reinterpret_cast<const bf16x8*>(&Vt[n * 16 + (lane & 15)][krow]);
                oacc[n] = __builtin_amdgcn_mfma_f32_16x16x32_bf16(pf, vf, oacc[n], 0, 0, 0);
            }
        }
    }
    // epilogue: O /= lsum, write f32 [b][s][h*64+dh]
    float* op = out + (size_t)b * S_ * DOUT_ + h * DH_;
    for (int r = 0; r < 4; ++r) {
        int row = s0 + wv * 16 + 4 * (lane >> 4) + r;
        float inv = 1.0f / lrow[r];
        for (int n = 0; n < 4; ++n)
            op[(size_t)row * DOUT_ + n * 16 + (lane & 15)] = oacc[n][r] * inv;
    }
}

// ---------------- kernel 4: LayerNorm over 512 features, wave per row, in-place
__global__ void lnorm(float* __restrict__ out, const float* __restrict__ gamma,
                      const float* __restrict__ beta) {
    int tid = threadIdx.x;
    int lane = tid & 63;
    int wv = tid >> 6;
    int row = blockIdx.x * 4 + wv;
    float* p = out + (size_t)row * DOUT_;
    float4 v0 = *reinterpret_cast<const float4*>(&p[lane * 8]);
    float4 v1 = *reinterpret_cast<const float4*>(&p[lane * 8 + 4]);
    float s = v0.x + v0.y + v0.z + v0.w + v1.x + v1.y + v1.z + v1.w;
    float sq = v0.x * v0.x + v0.y * v0.y + v0.z * v0.z + v0.w * v0.w +
               v1.x * v1.x + v1.y * v1.y + v1.z * v1.z + v1.w * v1.w;
    for (int off = 1; off < 64; off <<= 1) {
        s += __shfl_xor(s, off, 64);
        sq += __shfl_xor(sq, off, 64);
    }
    float mu = s * (1.0f / 512.0f);
    float var = sq * (1.0f / 512.0f) - mu * mu;
    float rstd = rsqrtf(fmaxf(var, 0.f) + EPS_);
    float4 g0 = *reinterpret_cast<const float4*>(&gamma[lane * 8]);
    float4 g1 = *reinterpret_cast<const float4*>(&gamma[lane * 8 + 4]);
    float4 b0 = *reinterpret_cast<const float4*>(&beta[lane * 8]);
    float4 b1 = *reinterpret_cast<const float4*>(&beta[lane * 8 + 4]);
    float4 o0, o1;
    o0.x = (v0.x - mu) * rstd * g0.x + b0.x;
    o0.y = (v0.y - mu) * rstd * g0.y + b0.y;
    o0.z = (v0.z - mu) * rstd * g0.z + b0.z;
    o0.w = (v0.w - mu) * rstd * g0.w + b0.w;
    o1.x = (v1.x - mu) * rstd * g1.x + b1.x;
    o1.y = (v1.y - mu) * rstd * g1.y + b1.y;
    o1.z = (v1.z - mu) * rstd * g1.z + b1.z;
    o1.w = (v1.w - mu) * rstd * g1.w + b1.w;
    *reinterpret_cast<float4*>(&p[lane * 8]) = o0;
    *reinterpret_cast<float4*>(&p[lane * 8 + 4]) = o1;
}

extern "C" void kernel_launch(void* const* d_in, const int* in_sizes, int n_in,
                              void* d_out, int out_size, void* d_ws, size_t ws_size,
                              hipStream_t stream) {
    const float* q        = (const float*)d_in[0];
    const float* k        = (const float*)d_in[1];
    const float* v        = (const float*)d_in[2];
    const float* conv_w   = (const float*)d_in[3];
    const float* conv_b   = (const float*)d_in[4];
    const float* bn_gamma = (const float*)d_in[5];
    const float* bn_beta  = (const float*)d_in[6];
    const float* bn_mean  = (const float*)d_in[7];
    const float* bn_var   = (const float*)d_in[8];
    const float* ln_gamma = (const float*)d_in[9];
    const float* ln_beta  = (const float*)d_in[10];

    unsigned short* qh    = (unsigned short*)d_ws;
    unsigned short* kh    = qh + (size_t)B_ * S_ * DOUT_;
    unsigned short* vh    = kh + (size_t)B_ * S_ * DOUT_;
    unsigned short* w_eff = vh + (size_t)B_ * S_ * DOUT_;
    float* b_eff          = (float*)(w_eff + (size_t)7 * DOUT_ * DIN_);

    float* out = (float*)d_out;

    prep_w<<<dim3(7168), dim3(256), 0, stream>>>(conv_w, conv_b, bn_gamma, bn_beta,
                                                 bn_mean, bn_var, w_eff, b_eff);
    conv_bn<<<dim3(768), dim3(256), 0, stream>>>(q, k, v, w_eff, b_eff, qh);
    attn<<<dim3(1024), dim3(256), 0, stream>>>(qh, kh, vh, out);
    lnorm<<<dim3(2048), dim3(256), 0, stream>>>(out, ln_gamma, ln_beta);
}

// Round 5
// 264.523 us; speedup vs baseline: 1.2296x; 1.2296x over previous
//
#include <hip/hip_runtime.h>
#include <hip/hip_bf16.h>

// Self_Attention: conv1d(k=7,pad=3)+BN on q/k/v -> MHA (H=8, DH=64) -> LayerNorm
// R3 (2nd resubmit after infra failures): V pre-transposed by a dedicated
// kernel; attn stages K and Vt through the same verified gl_lds + XOR(row&7)
// swizzle; no tr_read; dbuf + counted vmcnt.

#define B_ 4
#define S_ 2048
#define DIN_ 512
#define DOUT_ 512
#define H_ 8
#define DH_ 64
#define EPS_ 1e-5f

using bf16x8 = __attribute__((ext_vector_type(8))) short;
using f32x4  = __attribute__((ext_vector_type(4))) float;

__device__ __forceinline__ unsigned short f2bf(float x) {
    union { float f; unsigned u; } v; v.f = x;
    unsigned r = v.u + 0x7FFF + ((v.u >> 16) & 1);
    return (unsigned short)(r >> 16);
}

typedef __attribute__((address_space(1))) const unsigned int GU32;
typedef __attribute__((address_space(3))) unsigned int LU32;
__device__ __forceinline__ void gl_lds16(const void* g, void* l) {
    __builtin_amdgcn_global_load_lds((GU32*)g, (LU32*)l, 16, 0, 0);
}

// ---------------- kernel 1: fold BN into weights, cast to bf16 [t][co][ci] ----
__global__ void prep_w(const float* __restrict__ w, const float* __restrict__ cb,
                       const float* __restrict__ gamma, const float* __restrict__ beta,
                       const float* __restrict__ mean, const float* __restrict__ var,
                       unsigned short* __restrict__ w_eff, float* __restrict__ b_eff) {
    int gid = blockIdx.x * blockDim.x + threadIdx.x;
    if (gid < DOUT_) {
        float sc = gamma[gid] * rsqrtf(var[gid] + EPS_);
        b_eff[gid] = (cb[gid] - mean[gid]) * sc + beta[gid];
    }
    int total = 7 * DOUT_ * DIN_;
    for (int i = gid; i < total; i += gridDim.x * blockDim.x) {
        int t = i / (DOUT_ * DIN_);
        int rem = i - t * (DOUT_ * DIN_);
        int co = rem >> 9;
        int ci = rem & 511;
        float sc = gamma[co] * rsqrtf(var[co] + EPS_);
        w_eff[i] = f2bf(w[(co * DIN_ + ci) * 7 + t] * sc);
    }
}

// ---------------- kernel 2: conv+BN as implicit GEMM (7 shifted K=512 GEMMs) --
__global__ void conv_bn(const float* __restrict__ q, const float* __restrict__ k,
                        const float* __restrict__ v,
                        const unsigned short* __restrict__ w_eff,
                        const float* __restrict__ b_eff,
                        unsigned short* __restrict__ out3) {
    __shared__ alignas(16) unsigned short As[134][72];
    __shared__ alignas(16) unsigned short Bs[128][72];

    int bid = blockIdx.x;
    int tensor = bid >> 8;
    int rem = bid & 255;
    int batch = rem >> 6;
    int stile = (rem >> 2) & 15;
    int cotile = rem & 3;
    const float* x = (tensor == 0) ? q : ((tensor == 1) ? k : v);
    x += (size_t)batch * S_ * DIN_;
    unsigned short* out = out3 + (size_t)tensor * (B_ * S_ * DOUT_) + (size_t)batch * S_ * DOUT_;
    int s0 = stile * 128;
    int co0 = cotile * 128;
    int tid = threadIdx.x;
    int lane = tid & 63;
    int wv = tid >> 6;
    int wrow = (wv >> 1) * 64;
    int wcol = (wv & 1) * 64;

    f32x4 acc[4][4] = {};

    for (int cic = 0; cic < 8; ++cic) {
        int ci0 = cic * 64;
        __syncthreads();
        for (int c = tid; c < 134 * 16; c += 256) {
            int ar = c >> 4;
            int cc = c & 15;
            int gr = s0 + ar - 3;
            float4 val = make_float4(0.f, 0.f, 0.f, 0.f);
            if (gr >= 0 && gr < S_)
                val = *reinterpret_cast<const float4*>(&x[(size_t)gr * DIN_ + ci0 + cc * 4]);
            unsigned short* d = &As[ar][cc * 4];
            d[0] = f2bf(val.x); d[1] = f2bf(val.y); d[2] = f2bf(val.z); d[3] = f2bf(val.w);
        }
        for (int t = 0; t < 7; ++t) {
            if (t) __syncthreads();
            for (int c = tid; c < 1024; c += 256) {
                int r = c >> 3;
                int cc = c & 7;
                *reinterpret_cast<uint4*>(&Bs[r][cc * 8]) =
                    *reinterpret_cast<const uint4*>(
                        &w_eff[(size_t)t * DOUT_ * DIN_ + (size_t)(co0 + r) * DIN_ + ci0 + cc * 8]);
            }
            __syncthreads();
            for (int kk = 0; kk < 2; ++kk) {
                int krow = kk * 32 + 8 * (lane >> 4);
                bf16x8 af[4], bfr[4];
                for (int m = 0; m < 4; ++m)
                    af[m] = *reinterpret_cast<const bf16x8*>(&As[wrow + m * 16 + (lane & 15) + t][krow]);
                for (int n = 0; n < 4; ++n)
                    bfr[n] = *reinterpret_cast<const bf16x8*>(&Bs[wcol + n * 16 + (lane & 15)][krow]);
                for (int m = 0; m < 4; ++m)
                    for (int n = 0; n < 4; ++n)
                        acc[m][n] = __builtin_amdgcn_mfma_f32_16x16x32_bf16(af[m], bfr[n], acc[m][n], 0, 0, 0);
            }
        }
    }
    float osc = (tensor == 0) ? 0.125f : 1.0f;
    for (int m = 0; m < 4; ++m) {
        int row = s0 + wrow + m * 16 + 4 * (lane >> 4);
        for (int n = 0; n < 4; ++n) {
            int col = co0 + wcol + n * 16 + (lane & 15);
            float be = b_eff[col];
            for (int r = 0; r < 4; ++r)
                out[(size_t)(row + r) * DOUT_ + col] = f2bf((acc[m][n][r] + be) * osc);
        }
    }
}

// ---------------- kernel 2b: transpose V per (b,h): [S][DH] -> [DH][S] --------
// LDS tile 64x64 bf16, chunk swizzle phys = dhc ^ (s&7) ^ ((s>>3)&7).
__global__ void transpose_v(const unsigned short* __restrict__ vh,
                            unsigned short* __restrict__ vt) {
    __shared__ alignas(16) unsigned short T[64 * 64];
    int bid = blockIdx.x;
    int stile = bid & 31;
    int bh = bid >> 5;
    int b = bh >> 3;
    int h = bh & 7;
    int s0 = stile * 64;
    const unsigned short* src = vh + ((size_t)b * S_ + s0) * DOUT_ + h * DH_;
    unsigned short* dst = vt + (size_t)bh * DH_ * S_ + s0;
    int tid = threadIdx.x;
#pragma unroll
    for (int it = 0; it < 2; ++it) {
        int idx = tid + it * 256;
        int s = idx >> 3, dhc = idx & 7;
        uint4 val = *reinterpret_cast<const uint4*>(&src[(size_t)s * DOUT_ + dhc * 8]);
        *reinterpret_cast<uint4*>(&T[s * 64 + ((dhc ^ (s & 7) ^ ((s >> 3) & 7)) << 3)]) = val;
    }
    __syncthreads();
#pragma unroll
    for (int it = 0; it < 2; ++it) {
        int idx = tid + it * 256;
        int dh = idx >> 3, sc = idx & 7;
        unsigned short tmp[8];
#pragma unroll
        for (int j = 0; j < 8; ++j) {
            int s = sc * 8 + j;
            tmp[j] = T[s * 64 + (((dh >> 3) ^ (s & 7) ^ ((s >> 3) & 7)) << 3) + (dh & 7)];
        }
        *reinterpret_cast<uint4*>(&dst[(size_t)dh * S_ + sc * 8]) =
            *reinterpret_cast<const uint4*>(tmp);
    }
}

// ---------------- kernel 3: flash attention ----------------------------------
// K LDS:  [64 keys][128B], phys chunk = logical ^ (key&7)   (gl_lds staged)
// Vt LDS: [64 dh ][128B], phys chunk = logical ^ (dh&7)     (gl_lds staged)
// Ps:     [16 q][128B]/wave, phys chunk = logical ^ (row&7) ^ (row>>3)
__global__ __launch_bounds__(256, 4) void attn(const unsigned short* __restrict__ qh,
                     const unsigned short* __restrict__ kh,
                     const unsigned short* __restrict__ vt,
                     float* __restrict__ out) {
    __shared__ alignas(16) unsigned short Ks[2][64 * 64];
    __shared__ alignas(16) unsigned short Vs[2][64 * 64];
    __shared__ alignas(16) unsigned short Ps[4][16 * 64];

    const int tid = threadIdx.x;
    const int l = tid & 63;
    const int wv = tid >> 6;
    const int g = l >> 4;
    const int c16 = l & 15;

    const int bid = blockIdx.x;
    const int qt = bid & 31;
    const int bh = bid >> 5;
    const int b = bh >> 3;
    const int h = bh & 7;
    const int s0 = qt * 64;

    const unsigned short* qp = qh + (size_t)b * S_ * DOUT_ + h * DH_;
    const unsigned short* kp = kh + (size_t)b * S_ * DOUT_ + h * DH_;
    const unsigned short* vp = vt + (size_t)bh * DH_ * S_;

    bf16x8 qf[2];
    {
        int row = s0 + wv * 16 + c16;
        qf[0] = *reinterpret_cast<const bf16x8*>(&qp[(size_t)row * DOUT_ + 8 * g]);
        qf[1] = *reinterpret_cast<const bf16x8*>(&qp[(size_t)row * DOUT_ + 32 + 8 * g]);
    }

    const int l3 = l >> 3;
    const int kchunk8 = ((l & 7) ^ l3) * 8;   // source chunk (elems) for swizzled stage

#define STAGE(kt, buf) do {                                                          \
        const unsigned short* kgp = kp + (size_t)(kt) * 64 * DOUT_;                  \
        const unsigned short* vgp = vp + (size_t)(kt) * 64;                          \
        _Pragma("unroll")                                                            \
        for (int i = 0; i < 2; ++i) {                                                \
            int K0 = wv * 16 + i * 8;                                                \
            gl_lds16(kgp + (size_t)(K0 + l3) * DOUT_ + kchunk8, &Ks[buf][K0 * 64]);  \
            gl_lds16(vgp + (size_t)(K0 + l3) * S_   + kchunk8, &Vs[buf][K0 * 64]);   \
        }                                                                            \
    } while (0)

    f32x4 oacc[4] = {};
    float mrow[4], lrow[4];
#pragma unroll
    for (int r = 0; r < 4; ++r) { mrow[r] = -1e30f; lrow[r] = 0.f; }

    char* PsB = (char*)&Ps[wv][0];

    STAGE(0, 0);

    const int NT = S_ / 64;
    for (int kt = 0; kt < NT; ++kt) {
        const int cur = kt & 1;
        if (kt + 1 < NT) {
            STAGE(kt + 1, 1 - cur);
            asm volatile("s_waitcnt vmcnt(4)" ::: "memory");
        } else {
            asm volatile("s_waitcnt vmcnt(0)" ::: "memory");
        }
        __builtin_amdgcn_s_barrier();

        // ---- S = Q K^T ----
        const char* KsB = (const char*)&Ks[cur][0];
        f32x4 sf[4] = {};
#pragma unroll
        for (int kk = 0; kk < 2; ++kk) {
            bf16x8 kf[4];
#pragma unroll
            for (int n = 0; n < 4; ++n)
                kf[n] = *reinterpret_cast<const bf16x8*>(
                    KsB + (n * 16 + c16) * 128 + (((4 * kk + g) ^ (l & 7)) << 4));
            __builtin_amdgcn_s_setprio(1);
#pragma unroll
            for (int n = 0; n < 4; ++n)
                sf[n] = __builtin_amdgcn_mfma_f32_16x16x32_bf16(qf[kk], kf[n], sf[n], 0, 0, 0);
            __builtin_amdgcn_s_setprio(0);
        }

        // ---- online softmax (rows r: q = 4g+r, cols: key = n*16+c16) ----
        float mnew[4], corr[4];
#pragma unroll
        for (int r = 0; r < 4; ++r) {
            float mx = fmaxf(fmaxf(sf[0][r], sf[1][r]), fmaxf(sf[2][r], sf[3][r]));
            mx = fmaxf(mx, __shfl_xor(mx, 1, 64));
            mx = fmaxf(mx, __shfl_xor(mx, 2, 64));
            mx = fmaxf(mx, __shfl_xor(mx, 4, 64));
            mx = fmaxf(mx, __shfl_xor(mx, 8, 64));
            mnew[r] = fmaxf(mrow[r], mx);
            corr[r] = __expf(mrow[r] - mnew[r]);
            mrow[r] = mnew[r];
        }
        float rs[4] = {0.f, 0.f, 0.f, 0.f};
#pragma unroll
        for (int n = 0; n < 4; ++n)
#pragma unroll
            for (int r = 0; r < 4; ++r) {
                float p = __expf(sf[n][r] - mnew[r]);
                sf[n][r] = p;
                rs[r] += p;
            }
#pragma unroll
        for (int r = 0; r < 4; ++r) {
            rs[r] += __shfl_xor(rs[r], 1, 64);
            rs[r] += __shfl_xor(rs[r], 2, 64);
            rs[r] += __shfl_xor(rs[r], 4, 64);
            rs[r] += __shfl_xor(rs[r], 8, 64);
            lrow[r] = lrow[r] * corr[r] + rs[r];
            oacc[0][r] *= corr[r];
            oacc[1][r] *= corr[r];
            oacc[2][r] *= corr[r];
            oacc[3][r] *= corr[r];
        }

        // ---- P -> LDS (row = 4g+r, col = key = n*16+c16), swizzled ----
#pragma unroll
        for (int n = 0; n < 4; ++n) {
            int cb = 2 * n + (c16 >> 3);
#pragma unroll
            for (int r = 0; r < 4; ++r) {
                int row = 4 * g + r;
                int phys = cb ^ (row & 7) ^ (row >> 3);
                *(unsigned short*)(PsB + row * 128 + (phys << 4) + ((l & 7) << 1)) =
                    f2bf(sf[n][r]);
            }
        }

        // ---- O += P V (Vt as B-operand, same read form as K) ----
        const char* VsB = (const char*)&Vs[cur][0];
#pragma unroll
        for (int kk = 0; kk < 2; ++kk) {
            int physr = (4 * kk + g) ^ (c16 & 7) ^ (c16 >> 3);
            bf16x8 pf = *reinterpret_cast<const bf16x8*>(PsB + c16 * 128 + (physr << 4));
            bf16x8 vfr[4];
#pragma unroll
            for (int n = 0; n < 4; ++n)
                vfr[n] = *reinterpret_cast<const bf16x8*>(
                    VsB + (n * 16 + c16) * 128 + (((4 * kk + g) ^ (l & 7)) << 4));
            __builtin_amdgcn_s_setprio(1);
#pragma unroll
            for (int n = 0; n < 4; ++n)
                oacc[n] = __builtin_amdgcn_mfma_f32_16x16x32_bf16(pf, vfr[n], oacc[n], 0, 0, 0);
            __builtin_amdgcn_s_setprio(0);
        }
        __builtin_amdgcn_s_barrier();
    }

    float* op = out + (size_t)b * S_ * DOUT_ + h * DH_;
#pragma unroll
    for (int r = 0; r < 4; ++r) {
        int row = s0 + wv * 16 + 4 * g + r;
        float inv = 1.0f / lrow[r];
#pragma unroll
        for (int n = 0; n < 4; ++n)
            op[(size_t)row * DOUT_ + n * 16 + c16] = oacc[n][r] * inv;
    }
#undef STAGE
}

// ---------------- kernel 4: LayerNorm over 512 features, wave per row --------
__global__ void lnorm(float* __restrict__ out, const float* __restrict__ gamma,
                      const float* __restrict__ beta) {
    int tid = threadIdx.x;
    int lane = tid & 63;
    int wv = tid >> 6;
    int row = blockIdx.x * 4 + wv;
    float* p = out + (size_t)row * DOUT_;
    float4 v0 = *reinterpret_cast<const float4*>(&p[lane * 8]);
    float4 v1 = *reinterpret_cast<const float4*>(&p[lane * 8 + 4]);
    float s = v0.x + v0.y + v0.z + v0.w + v1.x + v1.y + v1.z + v1.w;
    float sq = v0.x * v0.x + v0.y * v0.y + v0.z * v0.z + v0.w * v0.w +
               v1.x * v1.x + v1.y * v1.y + v1.z * v1.z + v1.w * v1.w;
    for (int off = 1; off < 64; off <<= 1) {
        s += __shfl_xor(s, off, 64);
        sq += __shfl_xor(sq, off, 64);
    }
    float mu = s * (1.0f / 512.0f);
    float var = sq * (1.0f / 512.0f) - mu * mu;
    float rstd = rsqrtf(fmaxf(var, 0.f) + EPS_);
    float4 g0 = *reinterpret_cast<const float4*>(&gamma[lane * 8]);
    float4 g1 = *reinterpret_cast<const float4*>(&gamma[lane * 8 + 4]);
    float4 b0 = *reinterpret_cast<const float4*>(&beta[lane * 8]);
    float4 b1 = *reinterpret_cast<const float4*>(&beta[lane * 8 + 4]);
    float4 o0, o1;
    o0.x = (v0.x - mu) * rstd * g0.x + b0.x;
    o0.y = (v0.y - mu) * rstd * g0.y + b0.y;
    o0.z = (v0.z - mu) * rstd * g0.z + b0.z;
    o0.w = (v0.w - mu) * rstd * g0.w + b0.w;
    o1.x = (v1.x - mu) * rstd * g1.x + b1.x;
    o1.y = (v1.y - mu) * rstd * g1.y + b1.y;
    o1.z = (v1.z - mu) * rstd * g1.z + b1.z;
    o1.w = (v1.w - mu) * rstd * g1.w + b1.w;
    *reinterpret_cast<float4*>(&p[lane * 8]) = o0;
    *reinterpret_cast<float4*>(&p[lane * 8 + 4]) = o1;
}

extern "C" void kernel_launch(void* const* d_in, const int* in_sizes, int n_in,
                              void* d_out, int out_size, void* d_ws, size_t ws_size,
                              hipStream_t stream) {
    const float* q        = (const float*)d_in[0];
    const float* k        = (const float*)d_in[1];
    const float* v        = (const float*)d_in[2];
    const float* conv_w   = (const float*)d_in[3];
    const float* conv_b   = (const float*)d_in[4];
    const float* bn_gamma = (const float*)d_in[5];
    const float* bn_beta  = (const float*)d_in[6];
    const float* bn_mean  = (const float*)d_in[7];
    const float* bn_var   = (const float*)d_in[8];
    const float* ln_gamma = (const float*)d_in[9];
    const float* ln_beta  = (const float*)d_in[10];

    unsigned short* qh    = (unsigned short*)d_ws;
    unsigned short* kh    = qh + (size_t)B_ * S_ * DOUT_;
    unsigned short* vh    = kh + (size_t)B_ * S_ * DOUT_;
    unsigned short* w_eff = vh + (size_t)B_ * S_ * DOUT_;
    float* b_eff          = (float*)(w_eff + (size_t)7 * DOUT_ * DIN_);
    unsigned short* vt    = (unsigned short*)(b_eff + DOUT_);

    float* out = (float*)d_out;

    prep_w<<<dim3(7168), dim3(256), 0, stream>>>(conv_w, conv_b, bn_gamma, bn_beta,
                                                 bn_mean, bn_var, w_eff, b_eff);
    conv_bn<<<dim3(768), dim3(256), 0, stream>>>(q, k, v, w_eff, b_eff, qh);
    transpose_v<<<dim3(1024), dim3(256), 0, stream>>>(vh, vt);
    attn<<<dim3(1024), dim3(256), 0, stream>>>(qh, kh, vt, out);
    lnorm<<<dim3(2048), dim3(256), 0, stream>>>(out, ln_gamma, ln_beta);
}

// Round 6
// 217.071 us; speedup vs baseline: 1.4983x; 1.2186x over previous
//
#include <hip/hip_runtime.h>
#include <hip/hip_bf16.h>

// Self_Attention: conv1d(k=7,pad=3)+BN on q/k/v -> MHA (H=8, DH=64) -> LayerNorm
// R6: conv rewritten as gl_lds-staged implicit GEMM (A dbuf + B tri-buf,
// single barrier/iter, counted vmcnt, XOR swizzle, 64x128 wave tiles);
// new cast_x pre-pass (f32->bf16 padded); XCD-chunked block swizzles.

#define B_ 4
#define S_ 2048
#define DIN_ 512
#define DOUT_ 512
#define H_ 8
#define DH_ 64
#define EPS_ 1e-5f
#define SP_ 2054   // S + 6 halo rows

using bf16x8 = __attribute__((ext_vector_type(8))) short;
using f32x4  = __attribute__((ext_vector_type(4))) float;

__device__ __forceinline__ unsigned short f2bf(float x) {
    union { float f; unsigned u; } v; v.f = x;
    unsigned r = v.u + 0x7FFF + ((v.u >> 16) & 1);
    return (unsigned short)(r >> 16);
}

__device__ __forceinline__ unsigned cvt2(float lo, float hi) {
    unsigned r;
    asm("v_cvt_pk_bf16_f32 %0, %1, %2" : "=v"(r) : "v"(lo), "v"(hi));
    return r;
}

typedef __attribute__((address_space(1))) const unsigned int GU32;
typedef __attribute__((address_space(3))) unsigned int LU32;
__device__ __forceinline__ void gl_lds16(const void* g, void* l) {
    __builtin_amdgcn_global_load_lds((GU32*)g, (LU32*)l, 16, 0, 0);
}

// ---------------- kernel 0: cast q/k/v f32 -> bf16 padded [3][4][SP][512] ----
__global__ void cast_x(const float* __restrict__ q, const float* __restrict__ k,
                       const float* __restrict__ v, unsigned short* __restrict__ xb) {
    int i = blockIdx.x * 256 + threadIdx.x;      // one 8-elem chunk per thread
    int row = i >> 6;                            // 0 .. 3*4*SP-1
    int cin = (i & 63) * 8;
    int tb = row / SP_;
    int pr = row - tb * SP_;
    int tensor = tb >> 2;
    int b = tb & 3;
    unsigned short* dst = xb + (size_t)row * DIN_ + cin;
    if (pr < 3 || pr >= SP_ - 3) {
        *reinterpret_cast<uint4*>(dst) = make_uint4(0, 0, 0, 0);
    } else {
        const float* src = (tensor == 0 ? q : (tensor == 1 ? k : v)) +
                           ((size_t)b * S_ + (pr - 3)) * DIN_ + cin;
        float4 a0 = *reinterpret_cast<const float4*>(src);
        float4 a1 = *reinterpret_cast<const float4*>(src + 4);
        uint4 o;
        o.x = cvt2(a0.x, a0.y); o.y = cvt2(a0.z, a0.w);
        o.z = cvt2(a1.x, a1.y); o.w = cvt2(a1.z, a1.w);
        *reinterpret_cast<uint4*>(dst) = o;
    }
}

// ---------------- kernel 1: fold BN into weights, cast to bf16 [t][co][ci] ----
__global__ void prep_w(const float* __restrict__ w, const float* __restrict__ cb,
                       const float* __restrict__ gamma, const float* __restrict__ beta,
                       const float* __restrict__ mean, const float* __restrict__ var,
                       unsigned short* __restrict__ w_eff, float* __restrict__ b_eff) {
    int gid = blockIdx.x * blockDim.x + threadIdx.x;
    if (gid < DOUT_) {
        float sc = gamma[gid] * rsqrtf(var[gid] + EPS_);
        b_eff[gid] = (cb[gid] - mean[gid]) * sc + beta[gid];
    }
    int total = 7 * DOUT_ * DIN_;
    for (int i = gid; i < total; i += gridDim.x * blockDim.x) {
        int t = i / (DOUT_ * DIN_);
        int rem = i - t * (DOUT_ * DIN_);
        int co = rem >> 9;
        int ci = rem & 511;
        float sc = gamma[co] * rsqrtf(var[co] + EPS_);
        w_eff[i] = f2bf(w[(co * DIN_ + ci) * 7 + t] * sc);
    }
}

// ---------------- kernel 2: conv+BN implicit GEMM, gl_lds pipelined ----------
// Block: 128 s-rows x 256 co. 4 waves, each 64x128 (4x8 frags of 16x16x32).
// A LDS: dbuf [2][192 rows][32ci], chunk swizzle ^(r&3), staged via gl_lds
//   (rows clamped to 133 -> junk rows never read).
// B LDS: tri-buf [3][256 co][32ci], same swizzle. Single barrier per iter.
__global__ __launch_bounds__(256, 2) void conv_bn(
        const unsigned short* __restrict__ xb,
        const unsigned short* __restrict__ w_eff,
        const float* __restrict__ b_eff,
        unsigned short* __restrict__ out3) {
    __shared__ alignas(16) unsigned short As[2][192 * 32];
    __shared__ alignas(16) unsigned short Bs[3][256 * 32];

    int orig = blockIdx.x;
    int bid = (orig & 7) * 48 + (orig >> 3);   // XCD-chunked, 384 = 8*48
    int tensor = bid >> 7;
    int rem = bid & 127;
    int batch = rem >> 5;
    int stile = (rem >> 1) & 15;
    int cotile = rem & 1;
    int s0 = stile * 128;
    int co0 = cotile * 256;

    const unsigned short* xp = xb + (size_t)(tensor * 4 + batch) * SP_ * DIN_;
    unsigned short* out = out3 + (size_t)tensor * (B_ * S_ * DOUT_) +
                          (size_t)batch * S_ * DOUT_;

    const int tid = threadIdx.x;
    const int l = tid & 63;
    const int wv = tid >> 6;
    const int g = l >> 4;
    const int c16 = l & 15;
    const int wrow = (wv >> 1) * 64;
    const int wcol = (wv & 1) * 128;

    const int dr4 = l >> 2;                       // staging row-in-group
    const int sch = ((l & 3) ^ (dr4 & 3)) << 3;   // swizzled source chunk (elems)

#define STAGE_A(cc, buf) do {                                                   \
        _Pragma("unroll")                                                       \
        for (int j = 0; j < 3; ++j) {                                           \
            int r0 = (wv * 3 + j) * 16;                                         \
            int rs = r0 + dr4; if (rs > 133) rs = 133;                          \
            gl_lds16(xp + (size_t)(s0 + rs) * DIN_ + (cc) * 32 + sch,           \
                     &As[buf][r0 * 32]);                                        \
        }                                                                       \
    } while (0)

#define STAGE_B(cc, t, buf) do {                                                \
        const unsigned short* wp = w_eff + (size_t)(t) * (DOUT_ * DIN_) +       \
                                   (cc) * 32;                                   \
        _Pragma("unroll")                                                       \
        for (int j = 0; j < 4; ++j) {                                           \
            int r0 = (wv * 4 + j) * 16;                                         \
            gl_lds16(wp + (size_t)(co0 + r0 + dr4) * DIN_ + sch,                \
                     &Bs[buf][r0 * 32]);                                        \
        }                                                                       \
    } while (0)

    f32x4 acc[4][8] = {};

    STAGE_A(0, 0);
    STAGE_B(0, 0, 0);
    int bcur = 0;

    for (int cc = 0; cc < 16; ++cc) {
        const int ca = cc & 1;
        for (int t = 0; t < 7; ++t) {
            int bnext = bcur + 1; if (bnext == 3) bnext = 0;
            if (t < 6) {
                STAGE_B(cc, t + 1, bnext);
                asm volatile("s_waitcnt vmcnt(4)" ::: "memory");
            } else if (cc < 15) {
                STAGE_B(cc + 1, 0, bnext);
                STAGE_A(cc + 1, ca ^ 1);
                asm volatile("s_waitcnt vmcnt(7)" ::: "memory");
            } else {
                asm volatile("s_waitcnt vmcnt(0)" ::: "memory");
            }
            __builtin_amdgcn_s_barrier();

            const unsigned short* Ab = &As[ca][0];
            const unsigned short* Bb = &Bs[bcur][0];
            bf16x8 af[4], bfv[8];
#pragma unroll
            for (int m = 0; m < 4; ++m) {
                int r = wrow + m * 16 + c16 + t;
                af[m] = *reinterpret_cast<const bf16x8*>(
                    &Ab[r * 32 + ((g ^ (r & 3)) << 3)]);
            }
#pragma unroll
            for (int n = 0; n < 8; ++n) {
                int rb = wcol + n * 16 + c16;
                bfv[n] = *reinterpret_cast<const bf16x8*>(
                    &Bb[rb * 32 + ((g ^ (rb & 3)) << 3)]);
            }
            __builtin_amdgcn_s_setprio(1);
#pragma unroll
            for (int m = 0; m < 4; ++m)
#pragma unroll
                for (int n = 0; n < 8; ++n)
                    acc[m][n] = __builtin_amdgcn_mfma_f32_16x16x32_bf16(
                        af[m], bfv[n], acc[m][n], 0, 0, 0);
            __builtin_amdgcn_s_setprio(0);
            bcur = bnext;
        }
    }

    float osc = (tensor == 0) ? 0.125f : 1.0f;
#pragma unroll
    for (int m = 0; m < 4; ++m) {
        int rowb = s0 + wrow + m * 16 + 4 * g;
#pragma unroll
        for (int n = 0; n < 8; ++n) {
            int col = co0 + wcol + n * 16 + c16;
            float be = b_eff[col];
#pragma unroll
            for (int ri = 0; ri < 4; ++ri)
                out[(size_t)(rowb + ri) * DOUT_ + col] =
                    f2bf((acc[m][n][ri] + be) * osc);
        }
    }
#undef STAGE_A
#undef STAGE_B
}

// ---------------- kernel 2b: transpose V per (b,h): [S][DH] -> [DH][S] --------
__global__ void transpose_v(const unsigned short* __restrict__ vh,
                            unsigned short* __restrict__ vt) {
    __shared__ alignas(16) unsigned short T[64 * 64];
    int bid = blockIdx.x;
    int stile = bid & 31;
    int bh = bid >> 5;
    int b = bh >> 3;
    int h = bh & 7;
    int s0 = stile * 64;
    const unsigned short* src = vh + ((size_t)b * S_ + s0) * DOUT_ + h * DH_;
    unsigned short* dst = vt + (size_t)bh * DH_ * S_ + s0;
    int tid = threadIdx.x;
#pragma unroll
    for (int it = 0; it < 2; ++it) {
        int idx = tid + it * 256;
        int s = idx >> 3, dhc = idx & 7;
        uint4 val = *reinterpret_cast<const uint4*>(&src[(size_t)s * DOUT_ + dhc * 8]);
        *reinterpret_cast<uint4*>(&T[s * 64 + ((dhc ^ (s & 7) ^ ((s >> 3) & 7)) << 3)]) = val;
    }
    __syncthreads();
#pragma unroll
    for (int it = 0; it < 2; ++it) {
        int idx = tid + it * 256;
        int dh = idx >> 3, sc = idx & 7;
        unsigned short tmp[8];
#pragma unroll
        for (int j = 0; j < 8; ++j) {
            int s = sc * 8 + j;
            tmp[j] = T[s * 64 + (((dh >> 3) ^ (s & 7) ^ ((s >> 3) & 7)) << 3) + (dh & 7)];
        }
        *reinterpret_cast<uint4*>(&dst[(size_t)dh * S_ + sc * 8]) =
            *reinterpret_cast<const uint4*>(tmp);
    }
}

// ---------------- kernel 3: flash attention (R3-proven) ----------------------
__global__ __launch_bounds__(256, 4) void attn(const unsigned short* __restrict__ qh,
                     const unsigned short* __restrict__ kh,
                     const unsigned short* __restrict__ vt,
                     float* __restrict__ out) {
    __shared__ alignas(16) unsigned short Ks[2][64 * 64];
    __shared__ alignas(16) unsigned short Vs[2][64 * 64];
    __shared__ alignas(16) unsigned short Ps[4][16 * 64];

    const int tid = threadIdx.x;
    const int l = tid & 63;
    const int wv = tid >> 6;
    const int g = l >> 4;
    const int c16 = l & 15;

    const int orig = blockIdx.x;
    const int bid = ((orig & 7) << 7) + (orig >> 3);   // XCD-chunked, 1024 = 8*128
    const int qt = bid & 31;
    const int bh = bid >> 5;
    const int b = bh >> 3;
    const int h = bh & 7;
    const int s0 = qt * 64;

    const unsigned short* qp = qh + (size_t)b * S_ * DOUT_ + h * DH_;
    const unsigned short* kp = kh + (size_t)b * S_ * DOUT_ + h * DH_;
    const unsigned short* vp = vt + (size_t)bh * DH_ * S_;

    bf16x8 qf[2];
    {
        int row = s0 + wv * 16 + c16;
        qf[0] = *reinterpret_cast<const bf16x8*>(&qp[(size_t)row * DOUT_ + 8 * g]);
        qf[1] = *reinterpret_cast<const bf16x8*>(&qp[(size_t)row * DOUT_ + 32 + 8 * g]);
    }

    const int l3 = l >> 3;
    const int kchunk8 = ((l & 7) ^ l3) * 8;

#define STAGE(kt, buf) do {                                                          \
        const unsigned short* kgp = kp + (size_t)(kt) * 64 * DOUT_;                  \
        const unsigned short* vgp = vp + (size_t)(kt) * 64;                          \
        _Pragma("unroll")                                                            \
        for (int i = 0; i < 2; ++i) {                                                \
            int K0 = wv * 16 + i * 8;                                                \
            gl_lds16(kgp + (size_t)(K0 + l3) * DOUT_ + kchunk8, &Ks[buf][K0 * 64]);  \
            gl_lds16(vgp + (size_t)(K0 + l3) * S_   + kchunk8, &Vs[buf][K0 * 64]);   \
        }                                                                            \
    } while (0)

    f32x4 oacc[4] = {};
    float mrow[4], lrow[4];
#pragma unroll
    for (int r = 0; r < 4; ++r) { mrow[r] = -1e30f; lrow[r] = 0.f; }

    char* PsB = (char*)&Ps[wv][0];

    STAGE(0, 0);

    const int NT = S_ / 64;
    for (int kt = 0; kt < NT; ++kt) {
        const int cur = kt & 1;
        if (kt + 1 < NT) {
            STAGE(kt + 1, 1 - cur);
            asm volatile("s_waitcnt vmcnt(4)" ::: "memory");
        } else {
            asm volatile("s_waitcnt vmcnt(0)" ::: "memory");
        }
        __builtin_amdgcn_s_barrier();

        const char* KsB = (const char*)&Ks[cur][0];
        f32x4 sf[4] = {};
#pragma unroll
        for (int kk = 0; kk < 2; ++kk) {
            bf16x8 kf[4];
#pragma unroll
            for (int n = 0; n < 4; ++n)
                kf[n] = *reinterpret_cast<const bf16x8*>(
                    KsB + (n * 16 + c16) * 128 + (((4 * kk + g) ^ (l & 7)) << 4));
            __builtin_amdgcn_s_setprio(1);
#pragma unroll
            for (int n = 0; n < 4; ++n)
                sf[n] = __builtin_amdgcn_mfma_f32_16x16x32_bf16(qf[kk], kf[n], sf[n], 0, 0, 0);
            __builtin_amdgcn_s_setprio(0);
        }

        float mnew[4], corr[4];
#pragma unroll
        for (int r = 0; r < 4; ++r) {
            float mx = fmaxf(fmaxf(sf[0][r], sf[1][r]), fmaxf(sf[2][r], sf[3][r]));
            mx = fmaxf(mx, __shfl_xor(mx, 1, 64));
            mx = fmaxf(mx, __shfl_xor(mx, 2, 64));
            mx = fmaxf(mx, __shfl_xor(mx, 4, 64));
            mx = fmaxf(mx, __shfl_xor(mx, 8, 64));
            mnew[r] = fmaxf(mrow[r], mx);
            corr[r] = __expf(mrow[r] - mnew[r]);
            mrow[r] = mnew[r];
        }
        float rs[4] = {0.f, 0.f, 0.f, 0.f};
#pragma unroll
        for (int n = 0; n < 4; ++n)
#pragma unroll
            for (int r = 0; r < 4; ++r) {
                float p = __expf(sf[n][r] - mnew[r]);
                sf[n][r] = p;
                rs[r] += p;
            }
#pragma unroll
        for (int r = 0; r < 4; ++r) {
            rs[r] += __shfl_xor(rs[r], 1, 64);
            rs[r] += __shfl_xor(rs[r], 2, 64);
            rs[r] += __shfl_xor(rs[r], 4, 64);
            rs[r] += __shfl_xor(rs[r], 8, 64);
            lrow[r] = lrow[r] * corr[r] + rs[r];
            oacc[0][r] *= corr[r];
            oacc[1][r] *= corr[r];
            oacc[2][r] *= corr[r];
            oacc[3][r] *= corr[r];
        }

#pragma unroll
        for (int n = 0; n < 4; ++n) {
            int cb = 2 * n + (c16 >> 3);
#pragma unroll
            for (int r = 0; r < 4; ++r) {
                int row = 4 * g + r;
                int phys = cb ^ (row & 7) ^ (row >> 3);
                *(unsigned short*)(PsB + row * 128 + (phys << 4) + ((l & 7) << 1)) =
                    f2bf(sf[n][r]);
            }
        }

        const char* VsB = (const char*)&Vs[cur][0];
#pragma unroll
        for (int kk = 0; kk < 2; ++kk) {
            int physr = (4 * kk + g) ^ (c16 & 7) ^ (c16 >> 3);
            bf16x8 pf = *reinterpret_cast<const bf16x8*>(PsB + c16 * 128 + (physr << 4));
            bf16x8 vfr[4];
#pragma unroll
            for (int n = 0; n < 4; ++n)
                vfr[n] = *reinterpret_cast<const bf16x8*>(
                    VsB + (n * 16 + c16) * 128 + (((4 * kk + g) ^ (l & 7)) << 4));
            __builtin_amdgcn_s_setprio(1);
#pragma unroll
            for (int n = 0; n < 4; ++n)
                oacc[n] = __builtin_amdgcn_mfma_f32_16x16x32_bf16(pf, vfr[n], oacc[n], 0, 0, 0);
            __builtin_amdgcn_s_setprio(0);
        }
        __builtin_amdgcn_s_barrier();
    }

    float* op = out + (size_t)b * S_ * DOUT_ + h * DH_;
#pragma unroll
    for (int r = 0; r < 4; ++r) {
        int row = s0 + wv * 16 + 4 * g + r;
        float inv = 1.0f / lrow[r];
#pragma unroll
        for (int n = 0; n < 4; ++n)
            op[(size_t)row * DOUT_ + n * 16 + c16] = oacc[n][r] * inv;
    }
#undef STAGE
}

// ---------------- kernel 4: LayerNorm over 512 features, wave per row --------
__global__ void lnorm(float* __restrict__ out, const float* __restrict__ gamma,
                      const float* __restrict__ beta) {
    int tid = threadIdx.x;
    int lane = tid & 63;
    int wv = tid >> 6;
    int row = blockIdx.x * 4 + wv;
    float* p = out + (size_t)row * DOUT_;
    float4 v0 = *reinterpret_cast<const float4*>(&p[lane * 8]);
    float4 v1 = *reinterpret_cast<const float4*>(&p[lane * 8 + 4]);
    float s = v0.x + v0.y + v0.z + v0.w + v1.x + v1.y + v1.z + v1.w;
    float sq = v0.x * v0.x + v0.y * v0.y + v0.z * v0.z + v0.w * v0.w +
               v1.x * v1.x + v1.y * v1.y + v1.z * v1.z + v1.w * v1.w;
    for (int off = 1; off < 64; off <<= 1) {
        s += __shfl_xor(s, off, 64);
        sq += __shfl_xor(sq, off, 64);
    }
    float mu = s * (1.0f / 512.0f);
    float var = sq * (1.0f / 512.0f) - mu * mu;
    float rstd = rsqrtf(fmaxf(var, 0.f) + EPS_);
    float4 g0 = *reinterpret_cast<const float4*>(&gamma[lane * 8]);
    float4 g1 = *reinterpret_cast<const float4*>(&gamma[lane * 8 + 4]);
    float4 b0 = *reinterpret_cast<const float4*>(&beta[lane * 8]);
    float4 b1 = *reinterpret_cast<const float4*>(&beta[lane * 8 + 4]);
    float4 o0, o1;
    o0.x = (v0.x - mu) * rstd * g0.x + b0.x;
    o0.y = (v0.y - mu) * rstd * g0.y + b0.y;
    o0.z = (v0.z - mu) * rstd * g0.z + b0.z;
    o0.w = (v0.w - mu) * rstd * g0.w + b0.w;
    o1.x = (v1.x - mu) * rstd * g1.x + b1.x;
    o1.y = (v1.y - mu) * rstd * g1.y + b1.y;
    o1.z = (v1.z - mu) * rstd * g1.z + b1.z;
    o1.w = (v1.w - mu) * rstd * g1.w + b1.w;
    *reinterpret_cast<float4*>(&p[lane * 8]) = o0;
    *reinterpret_cast<float4*>(&p[lane * 8 + 4]) = o1;
}

extern "C" void kernel_launch(void* const* d_in, const int* in_sizes, int n_in,
                              void* d_out, int out_size, void* d_ws, size_t ws_size,
                              hipStream_t stream) {
    const float* q        = (const float*)d_in[0];
    const float* k        = (const float*)d_in[1];
    const float* v        = (const float*)d_in[2];
    const float* conv_w   = (const float*)d_in[3];
    const float* conv_b   = (const float*)d_in[4];
    const float* bn_gamma = (const float*)d_in[5];
    const float* bn_beta  = (const float*)d_in[6];
    const float* bn_mean  = (const float*)d_in[7];
    const float* bn_var   = (const float*)d_in[8];
    const float* ln_gamma = (const float*)d_in[9];
    const float* ln_beta  = (const float*)d_in[10];

    unsigned short* qh    = (unsigned short*)d_ws;
    unsigned short* kh    = qh + (size_t)B_ * S_ * DOUT_;
    unsigned short* vh    = kh + (size_t)B_ * S_ * DOUT_;
    unsigned short* w_eff = vh + (size_t)B_ * S_ * DOUT_;
    float* b_eff          = (float*)(w_eff + (size_t)7 * DOUT_ * DIN_);
    unsigned short* xb    = (unsigned short*)(b_eff + DOUT_);
    unsigned short* vt    = xb;   // alias: vt written only after conv consumed xb

    float* out = (float*)d_out;

    cast_x<<<dim3(6162), dim3(256), 0, stream>>>(q, k, v, xb);
    prep_w<<<dim3(7168), dim3(256), 0, stream>>>(conv_w, conv_b, bn_gamma, bn_beta,
                                                 bn_mean, bn_var, w_eff, b_eff);
    conv_bn<<<dim3(384), dim3(256), 0, stream>>>(xb, w_eff, b_eff, qh);
    transpose_v<<<dim3(1024), dim3(256), 0, stream>>>(vh, vt);
    attn<<<dim3(1024), dim3(256), 0, stream>>>(qh, kh, vt, out);
    lnorm<<<dim3(2048), dim3(256), 0, stream>>>(out, ln_gamma, ln_beta);
}